// Round 18
// baseline (387.239 us; speedup 1.0000x reference)
//
#include <hip/hip_runtime.h>
#include <stdint.h>

#define Bdim 2
#define Tdim 2048
#define Cdim 2048
#define Hdim 16
#define HKVdim 4
#define KVdim 512   // HKV*D
#define KT 32       // attn k-tile rows

typedef __attribute__((ext_vector_type(8))) short bf16x8;
typedef __attribute__((ext_vector_type(4))) float f32x4;

#define GLOAD16(gp, lp) __builtin_amdgcn_global_load_lds( \
    (const __attribute__((address_space(1))) void*)(gp),  \
    (__attribute__((address_space(3))) void*)(lp), 16, 0, 0)

__device__ __forceinline__ unsigned short f2bf(float f) {
  union { float f; unsigned u; } a; a.f = f;
  unsigned u = a.u + 0x7FFFu + ((a.u >> 16) & 1u);   // RNE
  return (unsigned short)(u >> 16);
}
__device__ __forceinline__ float bf2f(unsigned short h) {
  union { float f; unsigned u; } a; a.u = ((unsigned)h) << 16;
  return a.f;
}

// ---------------- split x into bf16 hi/lo (float4 vectorized) ----------------
__global__ void split_x_kernel(const float* __restrict__ x, unsigned short* __restrict__ hi,
                               unsigned short* __restrict__ lo, int n4) {
  int i = blockIdx.x * blockDim.x + threadIdx.x;
  int stride = gridDim.x * blockDim.x;
  const float4* x4 = (const float4*)x;
  ushort4* h4 = (ushort4*)hi;
  ushort4* l4 = (ushort4*)lo;
  for (; i < n4; i += stride) {
    float4 f = x4[i];
    ushort4 h, l;
    h.x = f2bf(f.x); l.x = f2bf(f.x - bf2f(h.x));
    h.y = f2bf(f.y); l.y = f2bf(f.y - bf2f(h.y));
    h.z = f2bf(f.z); l.z = f2bf(f.z - bf2f(h.z));
    h.w = f2bf(f.w); l.w = f2bf(f.w - bf2f(h.w));
    h4[i] = h; l4[i] = l;
  }
}

// ------- transpose (K,N) fp32 -> (N,K) bf16 hi (+lo); two sources via blockIdx.z ----
__global__ void transpose_split2_kernel(const float* __restrict__ in0, unsigned short* __restrict__ hi0,
                                        unsigned short* __restrict__ lo0,
                                        const float* __restrict__ in1, unsigned short* __restrict__ hi1,
                                        unsigned short* __restrict__ lo1, int K, int N) {
  __shared__ float tile[32][33];
  const float* in = blockIdx.z ? in1 : in0;
  unsigned short* hi = blockIdx.z ? hi1 : hi0;
  unsigned short* lo = blockIdx.z ? lo1 : lo0;
  int k0 = blockIdx.x * 32, n0 = blockIdx.y * 32;
  int tx = threadIdx.x, ty = threadIdx.y;
#pragma unroll
  for (int i = 0; i < 32; i += 8)
    tile[ty + i][tx] = in[(size_t)(k0 + ty + i) * N + n0 + tx];
  __syncthreads();
#pragma unroll
  for (int i = 0; i < 32; i += 8) {
    float f = tile[tx][ty + i];
    size_t o = (size_t)(n0 + ty + i) * K + k0 + tx;
    unsigned short hb = f2bf(f);
    hi[o] = hb;
    if (lo) lo[o] = f2bf(f - bf2f(hb));
  }
}

// ---------------- fused QKV GEMM + RoPE/split epilogue ----------------
// grid (32, 24): bn<16 q (3-term, rope); <20 k (3-term, rope); >=20 v (1-term,
// TRANSPOSED write -> vt). 3-term path: HI tiles double-buffered (32KB), LO tiles
// SINGLE-buffered (16KB) -> 48KB LDS. Mid-iteration __syncthreads() guards the
// lo-buffer overwrite. MFMA order per accumulator (hh, lh, hl) -> bit-identical.
// LDS bank swizzle (rule 21, both-sides): src chunk ^((lane>>3)&3), read chunk
// (lane>>4)^((ln15>>1)&3). Zero bank conflicts (r10-verified).
// No setprio here: m190 measured it slightly harmful on lockstep GEMMs.
__global__ __launch_bounds__(256) void qkv_gemm_kernel(
    const unsigned short* __restrict__ xhi, const unsigned short* __restrict__ xlo,
    const unsigned short* __restrict__ WqThi, const unsigned short* __restrict__ WqTlo,
    const unsigned short* __restrict__ WkThi, const unsigned short* __restrict__ WkTlo,
    const unsigned short* __restrict__ WvThi,
    const float* __restrict__ cs, const float* __restrict__ sn,
    unsigned short* __restrict__ qhi, unsigned short* __restrict__ qlo,
    unsigned short* __restrict__ khi, unsigned short* __restrict__ klo,
    unsigned short* __restrict__ vt)
{
  __shared__ alignas(16) unsigned short sAh[2][128 * 32];
  __shared__ alignas(16) unsigned short sBh[2][128 * 32];
  __shared__ alignas(16) unsigned short sAl[128 * 32];
  __shared__ alignas(16) unsigned short sBl[128 * 32];
  const int K = 2048;
  int tid = threadIdx.x;
  int wid = tid >> 6, lane = tid & 63;
  int bm = blockIdx.x, bn = blockIdx.y;
  int wr = wid >> 1, wc = wid & 1;
  int ln15 = lane & 15;
  int jsw = (((lane >> 4) ^ ((ln15 >> 1) & 3)) * 8);   // swizzled read chunk (shorts)
  int srow = lane >> 2;
  int scol = (((lane & 3) ^ ((lane >> 3) & 3)) * 8);   // swizzled source chunk (shorts)
  bool three = bn < 20;

  const unsigned short *Bh, *Bl = WqTlo;
  int brow;
  if (bn < 16)      { Bh = WqThi; Bl = WqTlo; brow = bn * 128; }
  else if (bn < 20) { Bh = WkThi; Bl = WkTlo; brow = (bn - 16) * 128; }
  else              { Bh = WvThi;             brow = (bn - 20) * 128; }

  f32x4 acc[4][4];
#pragma unroll
  for (int m = 0; m < 4; ++m)
#pragma unroll
    for (int n = 0; n < 4; ++n)
      acc[m][n] = f32x4{0.f, 0.f, 0.f, 0.f};

  const unsigned short* a0 = xhi + (size_t)(bm * 128 + wid * 32 + srow) * K + scol;
  const unsigned short* a1 = xlo + (size_t)(bm * 128 + wid * 32 + srow) * K + scol;
  const unsigned short* b0 = Bh + (size_t)(brow + wid * 32 + srow) * K + scol;
  const unsigned short* b1 = Bl + (size_t)(brow + wid * 32 + srow) * K + scol;
  int wlds = wid * 32 * 32;

  int nk = K >> 5;
  if (three) {
    auto stage_hi = [&](int buf, int kt) {
      const unsigned short* ak = a0 + kt * 32;
      const unsigned short* bk = b0 + kt * 32;
      GLOAD16(ak,          &sAh[buf][wlds]);
      GLOAD16(ak + 16 * K, &sAh[buf][wlds + 16 * 32]);
      GLOAD16(bk,          &sBh[buf][wlds]);
      GLOAD16(bk + 16 * K, &sBh[buf][wlds + 16 * 32]);
    };
    auto stage_lo = [&](int kt) {
      const unsigned short* alk = a1 + kt * 32;
      const unsigned short* blk = b1 + kt * 32;
      GLOAD16(alk,          &sAl[wlds]);
      GLOAD16(alk + 16 * K, &sAl[wlds + 16 * 32]);
      GLOAD16(blk,          &sBl[wlds]);
      GLOAD16(blk + 16 * K, &sBl[wlds + 16 * 32]);
    };
    stage_hi(0, 0);
    stage_lo(0);
    __syncthreads();
    int buf = 0;
    for (int kt = 0; kt < nk; ++kt) {
      bf16x8 afh[4], afl[4], bfh[4], bfl[4];
#pragma unroll
      for (int m = 0; m < 4; ++m) {
        afh[m] = *(const bf16x8*)&sAh[buf][(wr * 64 + m * 16 + ln15) * 32 + jsw];
        afl[m] = *(const bf16x8*)&sAl[(wr * 64 + m * 16 + ln15) * 32 + jsw];
      }
#pragma unroll
      for (int n = 0; n < 4; ++n) {
        bfh[n] = *(const bf16x8*)&sBh[buf][(wc * 64 + n * 16 + ln15) * 32 + jsw];
        bfl[n] = *(const bf16x8*)&sBl[(wc * 64 + n * 16 + ln15) * 32 + jsw];
      }
      __syncthreads();                            // all lo-reads in regs; no vmem pending
      if (kt + 1 < nk) { stage_hi(buf ^ 1, kt + 1); stage_lo(kt + 1); }  // fly during MFMAs
#pragma unroll
      for (int m = 0; m < 4; ++m)
#pragma unroll
        for (int n = 0; n < 4; ++n)
          acc[m][n] = __builtin_amdgcn_mfma_f32_16x16x32_bf16(afh[m], bfh[n], acc[m][n], 0, 0, 0);
#pragma unroll
      for (int m = 0; m < 4; ++m)
#pragma unroll
        for (int n = 0; n < 4; ++n)
          acc[m][n] = __builtin_amdgcn_mfma_f32_16x16x32_bf16(afl[m], bfh[n], acc[m][n], 0, 0, 0);
#pragma unroll
      for (int m = 0; m < 4; ++m)
#pragma unroll
        for (int n = 0; n < 4; ++n)
          acc[m][n] = __builtin_amdgcn_mfma_f32_16x16x32_bf16(afh[m], bfl[n], acc[m][n], 0, 0, 0);
      __syncthreads();                            // drains vmcnt; next tiles resident
      buf ^= 1;
    }
  } else {
    auto stage1 = [&](int buf, int kt) {
      const unsigned short* ak = a0 + kt * 32;
      const unsigned short* bk = b0 + kt * 32;
      GLOAD16(ak,          &sAh[buf][wlds]);
      GLOAD16(ak + 16 * K, &sAh[buf][wlds + 16 * 32]);
      GLOAD16(bk,          &sBh[buf][wlds]);
      GLOAD16(bk + 16 * K, &sBh[buf][wlds + 16 * 32]);
    };
    stage1(0, 0);
    __syncthreads();
    int buf = 0;
    for (int kt = 0; kt < nk; ++kt) {
      bf16x8 afh[4], bfh[4];
#pragma unroll
      for (int m = 0; m < 4; ++m)
        afh[m] = *(const bf16x8*)&sAh[buf][(wr * 64 + m * 16 + ln15) * 32 + jsw];
#pragma unroll
      for (int n = 0; n < 4; ++n)
        bfh[n] = *(const bf16x8*)&sBh[buf][(wc * 64 + n * 16 + ln15) * 32 + jsw];
      if (kt + 1 < nk) stage1(buf ^ 1, kt + 1);
#pragma unroll
      for (int m = 0; m < 4; ++m)
#pragma unroll
        for (int n = 0; n < 4; ++n)
          acc[m][n] = __builtin_amdgcn_mfma_f32_16x16x32_bf16(afh[m], bfh[n], acc[m][n], 0, 0, 0);
      __syncthreads();
      buf ^= 1;
    }
  }

  int orow0 = bm * 128 + wr * 64 + (lane >> 4) * 4;
  if (bn < 20) {
    // RoPE + split epilogue. d = wc*64 + n*16 + ln15; partner d+-32 is acc[m][n+-2].
    int nh = (bn < 16) ? Hdim : HKVdim;
    int h  = (bn < 16) ? bn : bn - 16;
    unsigned short* oph = (bn < 16) ? qhi : khi;
    unsigned short* opl = (bn < 16) ? qlo : klo;
#pragma unroll
    for (int m = 0; m < 4; ++m)
#pragma unroll
      for (int r = 0; r < 4; ++r) {
        int row = orow0 + m * 16 + r;
        int t = row & (Tdim - 1), b = row >> 11;
        size_t obase = (((size_t)(b * nh + h)) * Tdim + t) * 128;
#pragma unroll
        for (int n = 0; n < 4; ++n) {
          int d = wc * 64 + n * 16 + ln15;
          float o;
          if (wc == 0) {
            float c = cs[t * 64 + d], s = sn[t * 64 + d];
            o = (n < 2) ? (acc[m][n][r] * c - acc[m][n + 2][r] * s)
                        : (acc[m][n][r] * c + acc[m][n - 2][r] * s);
          } else o = acc[m][n][r];
          unsigned short hb = f2bf(o);
          oph[obase + d] = hb;
          opl[obase + d] = f2bf(o - bf2f(hb));
        }
      }
  } else {
    // v epilogue: write TRANSPOSED (b,g,d,t) directly; acc[m][n][0..3] = 4
    // consecutive t for one d -> ushort4 store.
    int g = bn - 20;
#pragma unroll
    for (int m = 0; m < 4; ++m) {
      int row0 = orow0 + m * 16;               // multiple of 4
      int t0 = row0 & (Tdim - 1), b = row0 >> 11;
#pragma unroll
      for (int n = 0; n < 4; ++n) {
        int d = wc * 64 + n * 16 + ln15;
        ushort4 v4;
        v4.x = f2bf(acc[m][n][0]);
        v4.y = f2bf(acc[m][n][1]);
        v4.z = f2bf(acc[m][n][2]);
        v4.w = f2bf(acc[m][n][3]);
        *(ushort4*)&vt[(((size_t)(b * HKVdim + g)) * 128 + d) * Tdim + t0] = v4;
      }
    }
  }
}

// ---------------- Wo GEMM: out(M,2048) = yb(M,2048) @ WoT^T, fp32 out, dbuf ----------
__global__ __launch_bounds__(256) void gemm_wo_kernel(
    const unsigned short* __restrict__ A, const unsigned short* __restrict__ Bt,
    float* __restrict__ C)
{
  __shared__ alignas(16) unsigned short sA[2][128 * 32];
  __shared__ alignas(16) unsigned short sB[2][128 * 32];
  const int K = 2048, ldc = 2048;
  int tid = threadIdx.x;
  int wid = tid >> 6, lane = tid & 63;
  int bm = blockIdx.x, bn = blockIdx.y;
  int wr = wid >> 1, wc = wid & 1;
  int ln15 = lane & 15;
  int jsw = (((lane >> 4) ^ ((ln15 >> 1) & 3)) * 8);
  int srow = lane >> 2;
  int scol = (((lane & 3) ^ ((lane >> 3) & 3)) * 8);

  f32x4 acc[4][4];
#pragma unroll
  for (int m = 0; m < 4; ++m)
#pragma unroll
    for (int n = 0; n < 4; ++n)
      acc[m][n] = f32x4{0.f, 0.f, 0.f, 0.f};

  const unsigned short* a0 = A + (size_t)(bm * 128 + wid * 32 + srow) * K + scol;
  const unsigned short* b0 = Bt + (size_t)(bn * 128 + wid * 32 + srow) * K + scol;
  int wlds = wid * 32 * 32;

  auto stage = [&](int buf, int kt) {
    const unsigned short* ak = a0 + kt * 32;
    const unsigned short* bk = b0 + kt * 32;
    GLOAD16(ak,          &sA[buf][wlds]);
    GLOAD16(ak + 16 * K, &sA[buf][wlds + 16 * 32]);
    GLOAD16(bk,          &sB[buf][wlds]);
    GLOAD16(bk + 16 * K, &sB[buf][wlds + 16 * 32]);
  };
  int nk = K >> 5;
  stage(0, 0);
  __syncthreads();
  int buf = 0;
  for (int kt = 0; kt < nk; ++kt) {
    bf16x8 af[4], bfv[4];
#pragma unroll
    for (int m = 0; m < 4; ++m)
      af[m] = *(const bf16x8*)&sA[buf][(wr * 64 + m * 16 + ln15) * 32 + jsw];
#pragma unroll
    for (int n = 0; n < 4; ++n)
      bfv[n] = *(const bf16x8*)&sB[buf][(wc * 64 + n * 16 + ln15) * 32 + jsw];
    if (kt + 1 < nk) stage(buf ^ 1, kt + 1);
#pragma unroll
    for (int m = 0; m < 4; ++m)
#pragma unroll
      for (int n = 0; n < 4; ++n)
        acc[m][n] = __builtin_amdgcn_mfma_f32_16x16x32_bf16(af[m], bfv[n], acc[m][n], 0, 0, 0);
    __syncthreads();
    buf ^= 1;
  }

  int orow0 = bm * 128 + wr * 64 + (lane >> 4) * 4;
  int ocol0 = bn * 128 + wc * 64 + ln15;
#pragma unroll
  for (int m = 0; m < 4; ++m)
#pragma unroll
    for (int n = 0; n < 4; ++n)
#pragma unroll
      for (int r = 0; r < 4; ++r)
        C[(size_t)(orow0 + m * 16 + r) * ldc + ocol0 + n * 16] = acc[m][n][r];
}

// ---------------- fused causal GQA attention with post-softmax gate ----------------
// QBLK=256, 16 waves (1024 thr), each wave owns 16 q-rows. Fixed-M softmax (M=8).
// Two-pass. Pass B iterates a COMPACTED list of live k-blocks (union over waves of
// the per-wave gate test) -- dead blocks cost zero staging/barriers. Bit-identical:
// waves still apply their own per-block test; processing order unchanged (ascending).
// launch_bounds(1024,4): r11 showed tighter bounds force VGPR spills (VGPR=40, 2x slow).
__global__ __launch_bounds__(1024, 4) void attn_kernel(
    const unsigned short* __restrict__ qhi, const unsigned short* __restrict__ qlo,
    const unsigned short* __restrict__ khi, const unsigned short* __restrict__ klo,
    const unsigned short* __restrict__ vt, const float* __restrict__ gate,
    unsigned short* __restrict__ y)
{
  __shared__ alignas(16) unsigned short sKh[2][KT * 128];
  __shared__ alignas(16) unsigned short sKl[2][KT * 128];
  __shared__ alignas(16) unsigned short sV[2][128 * KT];
  __shared__ alignas(16) unsigned short sP[16][16 * 40];
  __shared__ float sBM[16][64];
  __shared__ int liveFlag[64];
  __shared__ int sList[64];
  __shared__ int sCount;

  int qb = (gridDim.x - 1) - blockIdx.x;     // heavy blocks first
  int bh = blockIdx.y;
  int b = bh >> 4, h = bh & 15;
  int g = h >> 2;
  int t0 = qb * 256;
  int tid = threadIdx.x, wid = tid >> 6, lane = tid & 63;
  int ln15 = lane & 15, j16 = (lane >> 4) * 16, ro4 = (lane >> 4) * 4;
  const float cs2 = 0.08838834764831845f * 1.4426950408889634f;  // scale*log2(e)
  const float M2  = 8.0f * 1.4426950408889634f;

  const unsigned short* kh_base = khi + (((size_t)b * HKVdim + g) * Tdim) * 128;
  const unsigned short* kl_base = klo + (((size_t)b * HKVdim + g) * Tdim) * 128;
  const unsigned short* v_base  = vt  + (((size_t)b * HKVdim + g) * 128) * (size_t)Tdim;

  if (tid < 64) liveFlag[tid] = 0;

  bf16x8 aqh[4], aql[4];
  {
    size_t qoff = ((((size_t)b * Hdim + h) * Tdim) + t0 + wid * 16 + ln15) * 128 + (lane >> 4) * 8;
#pragma unroll
    for (int kf = 0; kf < 4; ++kf) {
      aqh[kf] = *(const bf16x8*)(qhi + qoff + kf * 32);
      aql[kf] = *(const bf16x8*)(qlo + qoff + kf * 32);
    }
  }
  float thr = 1.f / (1.f + expf(-gate[h]));

  int nkb = (qb + 1) * 8;
  int tq_lo = t0 + wid * 16;

  auto stageK = [&](int buf, int kb) {
    if (wid < 8) {
      int o = wid * 1024 + lane * 16;
      int row = o >> 8;
      int col = (o & 255) ^ ((row & 7) << 4);
      size_t goff = ((size_t)(kb * KT + row)) * 256 + col;
      GLOAD16((const char*)kh_base + goff, (char*)sKh[buf] + wid * 1024);
      GLOAD16((const char*)kl_base + goff, (char*)sKl[buf] + wid * 1024);
    }
  };
  auto stageV = [&](int buf, int kb) {
    if (wid >= 8) {
      int o = (wid - 8) * 1024 + lane * 16;
      int row = o >> 6;
      int col = (o & 63) ^ (((row ^ (row >> 2)) & 3) << 4);
      size_t goff = (size_t)row * (Tdim * 2) + (size_t)kb * 64 + col;
      GLOAD16((const char*)v_base + goff, (char*)sV[buf] + (wid - 8) * 1024);
    }
  };
  auto qk = [&](int buf, f32x4* s) {
    __builtin_amdgcn_s_setprio(1);
#pragma unroll
    for (int nf = 0; nf < 2; ++nf) {
      f32x4 a = {0.f, 0.f, 0.f, 0.f};
      int krow = nf * 16 + ln15;
      int sw = (krow & 7) << 4;
#pragma unroll
      for (int kf = 0; kf < 4; ++kf) {
        int boff = (kf * 64 + j16) ^ sw;
        bf16x8 bh_ = *(const bf16x8*)((const char*)sKh[buf] + krow * 256 + boff);
        bf16x8 bl_ = *(const bf16x8*)((const char*)sKl[buf] + krow * 256 + boff);
        a = __builtin_amdgcn_mfma_f32_16x16x32_bf16(aqh[kf], bh_, a, 0, 0, 0);
        a = __builtin_amdgcn_mfma_f32_16x16x32_bf16(aql[kf], bh_, a, 0, 0, 0);
        a = __builtin_amdgcn_mfma_f32_16x16x32_bf16(aqh[kf], bl_, a, 0, 0, 0);
      }
      s[nf] = a;
    }
    __builtin_amdgcn_s_setprio(0);
  };

  float lloc[4];
#pragma unroll
  for (int r = 0; r < 4; ++r) lloc[r] = 0.f;

  // ---- PASS A: l = sum 2^(s2-M2); per-block wave max for pass-B skip ----
  stageK(0, 0);
  __syncthreads();
  for (int kb = 0; kb < nkb; ++kb) {
    int buf = kb & 1;
    if (kb + 1 < nkb) stageK(buf ^ 1, kb + 1);
    if (kb * KT <= tq_lo + 15) {
      f32x4 s[2];
      qk(buf, s);
      float wmax = -1e30f;
      bool full = (kb * KT + KT - 1) <= tq_lo;   // wave-uniform: no masked entries
      if (full) {
#pragma unroll
        for (int nf = 0; nf < 2; ++nf)
#pragma unroll
          for (int r = 0; r < 4; ++r) {
            float v = s[nf][r] * cs2;
            wmax = fmaxf(wmax, v);
            lloc[r] += __builtin_exp2f(v - M2);
          }
      } else {
#pragma unroll
        for (int nf = 0; nf < 2; ++nf) {
          int tk = kb * KT + nf * 16 + ln15;
#pragma unroll
          for (int r = 0; r < 4; ++r) {
            int tq = tq_lo + ro4 + r;
            float v = (tk <= tq) ? s[nf][r] * cs2 : -1e30f;
            wmax = fmaxf(wmax, v);
            lloc[r] += __builtin_exp2f(v - M2);   // exp2(-1e30) == 0
          }
        }
      }
#pragma unroll
      for (int off = 1; off < 64; off <<= 1)
        wmax = fmaxf(wmax, __shfl_xor(wmax, off));
      if (lane == 0) sBM[wid][kb] = wmax;
    }
    __syncthreads();
  }

  // merge l across the 16 k-residue lanes (bits 0-3); build log2-space gate
  float lrow[4], lgate2[4];
#pragma unroll
  for (int r = 0; r < 4; ++r) {
    float l = lloc[r];
#pragma unroll
    for (int off = 1; off < 16; off <<= 1) l += __shfl_xor(l, off);
    lrow[r] = l;
    lgate2[r] = __log2f(thr * l) + M2;           // keep iff s2 >= lgate2
  }
  float lgmin = fminf(fminf(lgate2[0], lgate2[1]), fminf(lgate2[2], lgate2[3]));
  lgmin = fminf(lgmin, __shfl_xor(lgmin, 16));
  lgmin = fminf(lgmin, __shfl_xor(lgmin, 32));

  // ---- build compacted live-block list (union over waves) ----
  if (lane == 0) {
    for (int kb = 0; kb < nkb; ++kb)
      if (kb * KT <= tq_lo + 15 && sBM[wid][kb] >= lgmin) liveFlag[kb] = 1;
  }
  __syncthreads();
  if (tid == 0) {
    int c = 0;
    for (int kb = 0; kb < nkb; ++kb)
      if (liveFlag[kb]) sList[c++] = kb;
    sCount = c;
  }
  __syncthreads();
  int cnt = sCount;

  // ---- PASS B: iterate live blocks only; per-wave gate test unchanged ----
  f32x4 yacc[8];
#pragma unroll
  for (int n = 0; n < 8; ++n) yacc[n] = f32x4{0.f, 0.f, 0.f, 0.f};

  if (cnt > 0) { stageK(0, sList[0]); stageV(0, sList[0]); }
  __syncthreads();
  for (int i = 0; i < cnt; ++i) {
    int kb = sList[i];
    int buf = i & 1;
    if (i + 1 < cnt) { stageK(buf ^ 1, sList[i + 1]); stageV(buf ^ 1, sList[i + 1]); }
    if (kb * KT <= tq_lo + 15 && sBM[wid][kb] >= lgmin) {
      f32x4 s[2];
      qk(buf, s);
      bool anyk = false;
      float pv[2][4];
      bool full = (kb * KT + KT - 1) <= tq_lo;
#pragma unroll
      for (int nf = 0; nf < 2; ++nf) {
        int tk = kb * KT + nf * 16 + ln15;
#pragma unroll
        for (int r = 0; r < 4; ++r) {
          int tq = tq_lo + ro4 + r;
          float v = s[nf][r] * cs2;
          bool keep = (full || tk <= tq) && (v >= lgate2[r]);
          float p = 0.f;
          if (keep) { p = __builtin_exp2f(v - M2); anyk = true; }
          pv[nf][r] = p;
        }
      }
      if (__any(anyk)) {
#pragma unroll
        for (int nf = 0; nf < 2; ++nf)
#pragma unroll
          for (int r = 0; r < 4; ++r)
            sP[wid][(ro4 + r) * 40 + nf * 16 + ln15] = f2bf(pv[nf][r]);
        __builtin_amdgcn_s_setprio(1);
        bf16x8 pa = *(const bf16x8*)&sP[wid][ln15 * 40 + (lane >> 4) * 8];
#pragma unroll
        for (int nf2 = 0; nf2 < 8; ++nf2) {
          int vrow = nf2 * 16 + ln15;
          int vboff = j16 ^ (((vrow ^ (vrow >> 2)) & 3) << 4);
          bf16x8 vb = *(const bf16x8*)((const char*)sV[buf] + vrow * 64 + vboff);
          yacc[nf2] = __builtin_amdgcn_mfma_f32_16x16x32_bf16(pa, vb, yacc[nf2], 0, 0, 0);
        }
        __builtin_amdgcn_s_setprio(0);
      }
    }
    __syncthreads();
  }

  // epilogue: y (b,t,h,d) bf16
#pragma unroll
  for (int r = 0; r < 4; ++r) {
    int tq = t0 + wid * 16 + ro4 + r;
    float invl = 1.f / lrow[r];
    size_t base = ((size_t)(b * Tdim + tq)) * Cdim + h * 128;
#pragma unroll
    for (int nf2 = 0; nf2 < 8; ++nf2)
      y[base + nf2 * 16 + ln15] = f2bf(yacc[nf2][r] * invl);
  }
}

extern "C" void kernel_launch(void* const* d_in, const int* in_sizes, int n_in,
                              void* d_out, int out_size, void* d_ws, size_t ws_size,
                              hipStream_t stream)
{
  (void)in_sizes; (void)n_in; (void)out_size; (void)ws_size;
  const float* x    = (const float*)d_in[0];
  const float* cosT = (const float*)d_in[1];
  const float* sinT = (const float*)d_in[2];
  const float* Wq   = (const float*)d_in[3];
  const float* Wk   = (const float*)d_in[4];
  const float* Wv   = (const float*)d_in[5];
  const float* Wo   = (const float*)d_in[6];
  const float* gate = (const float*)d_in[7];
  float* out = (float*)d_out;

  char* ws = (char*)d_ws;
  size_t off = 0;
  auto alloc = [&](size_t bytes) -> char* {
    char* p = ws + off; off += (bytes + 255) & ~(size_t)255; return p;
  };
  const size_t NX = (size_t)Bdim * Tdim * Cdim;    // 8388608
  const size_t NK = (size_t)Bdim * Tdim * KVdim;   // 2097152

  unsigned short* xhi   = (unsigned short*)alloc(NX * 2);
  unsigned short* xlo   = (unsigned short*)alloc(NX * 2);
  unsigned short* WqThi = (unsigned short*)alloc((size_t)Cdim * Cdim * 2);
  unsigned short* WqTlo = (unsigned short*)alloc((size_t)Cdim * Cdim * 2);
  unsigned short* WkThi = (unsigned short*)alloc((size_t)Cdim * KVdim * 2);
  unsigned short* WkTlo = (unsigned short*)alloc((size_t)Cdim * KVdim * 2);
  unsigned short* WvThi = (unsigned short*)alloc((size_t)Cdim * KVdim * 2);
  unsigned short* WoThi = (unsigned short*)alloc((size_t)Cdim * Cdim * 2);
  unsigned short* qhi   = (unsigned short*)alloc(NX * 2);
  unsigned short* qlo   = (unsigned short*)alloc(NX * 2);
  unsigned short* khi   = (unsigned short*)alloc(NK * 2);
  unsigned short* klo   = (unsigned short*)alloc(NK * 2);
  unsigned short* vtr   = (unsigned short*)alloc(NK * 2);
  unsigned short* yb    = (unsigned short*)alloc(NX * 2);

  dim3 tb(32, 8);
  split_x_kernel<<<2048, 256, 0, stream>>>(x, xhi, xlo, (int)(NX >> 2));
  transpose_split2_kernel<<<dim3(64, 64, 2), tb, 0, stream>>>(
      Wq, WqThi, WqTlo, Wo, WoThi, nullptr, Cdim, Cdim);
  transpose_split2_kernel<<<dim3(64, 16, 2), tb, 0, stream>>>(
      Wk, WkThi, WkTlo, Wv, WvThi, nullptr, Cdim, KVdim);

  // q, k (split-3, rope+split fused) and v (1-term, transposed write) in one dispatch
  qkv_gemm_kernel<<<dim3(32, 24), 256, 0, stream>>>(
      xhi, xlo, WqThi, WqTlo, WkThi, WkTlo, WvThi,
      cosT, sinT, qhi, qlo, khi, klo, vtr);

  attn_kernel<<<dim3(8, 32), 1024, 0, stream>>>(qhi, qlo, khi, klo, vtr, gate, yb);

  gemm_wo_kernel<<<dim3(32, 16), 256, 0, stream>>>(yb, WoThi, out);
}

// Round 19
// 354.405 us; speedup vs baseline: 1.0926x; 1.0926x over previous
//
#include <hip/hip_runtime.h>
#include <stdint.h>

#define Bdim 2
#define Tdim 2048
#define Cdim 2048
#define Hdim 16
#define HKVdim 4
#define KVdim 512   // HKV*D
#define KT 32       // attn k-tile rows

typedef __attribute__((ext_vector_type(8))) short bf16x8;
typedef __attribute__((ext_vector_type(4))) float f32x4;

#define GLOAD16(gp, lp) __builtin_amdgcn_global_load_lds( \
    (const __attribute__((address_space(1))) void*)(gp),  \
    (__attribute__((address_space(3))) void*)(lp), 16, 0, 0)

__device__ __forceinline__ unsigned short f2bf(float f) {
  union { float f; unsigned u; } a; a.f = f;
  unsigned u = a.u + 0x7FFFu + ((a.u >> 16) & 1u);   // RNE
  return (unsigned short)(u >> 16);
}
__device__ __forceinline__ float bf2f(unsigned short h) {
  union { float f; unsigned u; } a; a.u = ((unsigned)h) << 16;
  return a.f;
}

// ---------------- split x into bf16 hi/lo (float4 vectorized) ----------------
__global__ void split_x_kernel(const float* __restrict__ x, unsigned short* __restrict__ hi,
                               unsigned short* __restrict__ lo, int n4) {
  int i = blockIdx.x * blockDim.x + threadIdx.x;
  int stride = gridDim.x * blockDim.x;
  const float4* x4 = (const float4*)x;
  ushort4* h4 = (ushort4*)hi;
  ushort4* l4 = (ushort4*)lo;
  for (; i < n4; i += stride) {
    float4 f = x4[i];
    ushort4 h, l;
    h.x = f2bf(f.x); l.x = f2bf(f.x - bf2f(h.x));
    h.y = f2bf(f.y); l.y = f2bf(f.y - bf2f(h.y));
    h.z = f2bf(f.z); l.z = f2bf(f.z - bf2f(h.z));
    h.w = f2bf(f.w); l.w = f2bf(f.w - bf2f(h.w));
    h4[i] = h; l4[i] = l;
  }
}

// ------- transpose (K,N) fp32 -> (N,K) bf16 hi (+lo); two sources via blockIdx.z ----
__global__ void transpose_split2_kernel(const float* __restrict__ in0, unsigned short* __restrict__ hi0,
                                        unsigned short* __restrict__ lo0,
                                        const float* __restrict__ in1, unsigned short* __restrict__ hi1,
                                        unsigned short* __restrict__ lo1, int K, int N) {
  __shared__ float tile[32][33];
  const float* in = blockIdx.z ? in1 : in0;
  unsigned short* hi = blockIdx.z ? hi1 : hi0;
  unsigned short* lo = blockIdx.z ? lo1 : lo0;
  int k0 = blockIdx.x * 32, n0 = blockIdx.y * 32;
  int tx = threadIdx.x, ty = threadIdx.y;
#pragma unroll
  for (int i = 0; i < 32; i += 8)
    tile[ty + i][tx] = in[(size_t)(k0 + ty + i) * N + n0 + tx];
  __syncthreads();
#pragma unroll
  for (int i = 0; i < 32; i += 8) {
    float f = tile[tx][ty + i];
    size_t o = (size_t)(n0 + ty + i) * K + k0 + tx;
    unsigned short hb = f2bf(f);
    hi[o] = hb;
    if (lo) lo[o] = f2bf(f - bf2f(hb));
  }
}

// ---------------- fused QKV GEMM + RoPE/split epilogue ----------------
// grid (32, 24): bn<16 q (3-term, rope); <20 k (3-term, rope); >=20 v (1-term,
// TRANSPOSED write -> vt). 3-term path: HI tiles double-buffered (32KB), LO tiles
// SINGLE-buffered (16KB) -> 48KB LDS. Mid-iteration __syncthreads() guards the
// lo-buffer overwrite. MFMA order per accumulator (hh, lh, hl) -> bit-identical.
// LDS bank swizzle (rule 21, both-sides): src chunk ^((lane>>3)&3), read chunk
// (lane>>4)^((ln15>>1)&3). Zero bank conflicts (r10-verified).
// setprio KEPT: r18 A/B measured removing it as -14% (mid-iter sync creates wave
// role diversity -> T5 mechanism applies, unlike m190's lockstep null).
__global__ __launch_bounds__(256) void qkv_gemm_kernel(
    const unsigned short* __restrict__ xhi, const unsigned short* __restrict__ xlo,
    const unsigned short* __restrict__ WqThi, const unsigned short* __restrict__ WqTlo,
    const unsigned short* __restrict__ WkThi, const unsigned short* __restrict__ WkTlo,
    const unsigned short* __restrict__ WvThi,
    const float* __restrict__ cs, const float* __restrict__ sn,
    unsigned short* __restrict__ qhi, unsigned short* __restrict__ qlo,
    unsigned short* __restrict__ khi, unsigned short* __restrict__ klo,
    unsigned short* __restrict__ vt)
{
  __shared__ alignas(16) unsigned short sAh[2][128 * 32];
  __shared__ alignas(16) unsigned short sBh[2][128 * 32];
  __shared__ alignas(16) unsigned short sAl[128 * 32];
  __shared__ alignas(16) unsigned short sBl[128 * 32];
  const int K = 2048;
  int tid = threadIdx.x;
  int wid = tid >> 6, lane = tid & 63;
  int bm = blockIdx.x, bn = blockIdx.y;
  int wr = wid >> 1, wc = wid & 1;
  int ln15 = lane & 15;
  int jsw = (((lane >> 4) ^ ((ln15 >> 1) & 3)) * 8);   // swizzled read chunk (shorts)
  int srow = lane >> 2;
  int scol = (((lane & 3) ^ ((lane >> 3) & 3)) * 8);   // swizzled source chunk (shorts)
  bool three = bn < 20;

  const unsigned short *Bh, *Bl = WqTlo;
  int brow;
  if (bn < 16)      { Bh = WqThi; Bl = WqTlo; brow = bn * 128; }
  else if (bn < 20) { Bh = WkThi; Bl = WkTlo; brow = (bn - 16) * 128; }
  else              { Bh = WvThi;             brow = (bn - 20) * 128; }

  f32x4 acc[4][4];
#pragma unroll
  for (int m = 0; m < 4; ++m)
#pragma unroll
    for (int n = 0; n < 4; ++n)
      acc[m][n] = f32x4{0.f, 0.f, 0.f, 0.f};

  const unsigned short* a0 = xhi + (size_t)(bm * 128 + wid * 32 + srow) * K + scol;
  const unsigned short* a1 = xlo + (size_t)(bm * 128 + wid * 32 + srow) * K + scol;
  const unsigned short* b0 = Bh + (size_t)(brow + wid * 32 + srow) * K + scol;
  const unsigned short* b1 = Bl + (size_t)(brow + wid * 32 + srow) * K + scol;
  int wlds = wid * 32 * 32;

  int nk = K >> 5;
  if (three) {
    auto stage_hi = [&](int buf, int kt) {
      const unsigned short* ak = a0 + kt * 32;
      const unsigned short* bk = b0 + kt * 32;
      GLOAD16(ak,          &sAh[buf][wlds]);
      GLOAD16(ak + 16 * K, &sAh[buf][wlds + 16 * 32]);
      GLOAD16(bk,          &sBh[buf][wlds]);
      GLOAD16(bk + 16 * K, &sBh[buf][wlds + 16 * 32]);
    };
    auto stage_lo = [&](int kt) {
      const unsigned short* alk = a1 + kt * 32;
      const unsigned short* blk = b1 + kt * 32;
      GLOAD16(alk,          &sAl[wlds]);
      GLOAD16(alk + 16 * K, &sAl[wlds + 16 * 32]);
      GLOAD16(blk,          &sBl[wlds]);
      GLOAD16(blk + 16 * K, &sBl[wlds + 16 * 32]);
    };
    stage_hi(0, 0);
    stage_lo(0);
    __syncthreads();
    int buf = 0;
    for (int kt = 0; kt < nk; ++kt) {
      bf16x8 afh[4], afl[4], bfh[4], bfl[4];
#pragma unroll
      for (int m = 0; m < 4; ++m) {
        afh[m] = *(const bf16x8*)&sAh[buf][(wr * 64 + m * 16 + ln15) * 32 + jsw];
        afl[m] = *(const bf16x8*)&sAl[(wr * 64 + m * 16 + ln15) * 32 + jsw];
      }
#pragma unroll
      for (int n = 0; n < 4; ++n) {
        bfh[n] = *(const bf16x8*)&sBh[buf][(wc * 64 + n * 16 + ln15) * 32 + jsw];
        bfl[n] = *(const bf16x8*)&sBl[(wc * 64 + n * 16 + ln15) * 32 + jsw];
      }
      __syncthreads();                            // all lo-reads in regs; no vmem pending
      if (kt + 1 < nk) { stage_hi(buf ^ 1, kt + 1); stage_lo(kt + 1); }  // fly during MFMAs
      __builtin_amdgcn_s_setprio(1);
#pragma unroll
      for (int m = 0; m < 4; ++m)
#pragma unroll
        for (int n = 0; n < 4; ++n)
          acc[m][n] = __builtin_amdgcn_mfma_f32_16x16x32_bf16(afh[m], bfh[n], acc[m][n], 0, 0, 0);
#pragma unroll
      for (int m = 0; m < 4; ++m)
#pragma unroll
        for (int n = 0; n < 4; ++n)
          acc[m][n] = __builtin_amdgcn_mfma_f32_16x16x32_bf16(afl[m], bfh[n], acc[m][n], 0, 0, 0);
#pragma unroll
      for (int m = 0; m < 4; ++m)
#pragma unroll
        for (int n = 0; n < 4; ++n)
          acc[m][n] = __builtin_amdgcn_mfma_f32_16x16x32_bf16(afh[m], bfl[n], acc[m][n], 0, 0, 0);
      __builtin_amdgcn_s_setprio(0);
      __syncthreads();                            // drains vmcnt; next tiles resident
      buf ^= 1;
    }
  } else {
    auto stage1 = [&](int buf, int kt) {
      const unsigned short* ak = a0 + kt * 32;
      const unsigned short* bk = b0 + kt * 32;
      GLOAD16(ak,          &sAh[buf][wlds]);
      GLOAD16(ak + 16 * K, &sAh[buf][wlds + 16 * 32]);
      GLOAD16(bk,          &sBh[buf][wlds]);
      GLOAD16(bk + 16 * K, &sBh[buf][wlds + 16 * 32]);
    };
    stage1(0, 0);
    __syncthreads();
    int buf = 0;
    for (int kt = 0; kt < nk; ++kt) {
      bf16x8 afh[4], bfh[4];
#pragma unroll
      for (int m = 0; m < 4; ++m)
        afh[m] = *(const bf16x8*)&sAh[buf][(wr * 64 + m * 16 + ln15) * 32 + jsw];
#pragma unroll
      for (int n = 0; n < 4; ++n)
        bfh[n] = *(const bf16x8*)&sBh[buf][(wc * 64 + n * 16 + ln15) * 32 + jsw];
      if (kt + 1 < nk) stage1(buf ^ 1, kt + 1);
      __builtin_amdgcn_s_setprio(1);
#pragma unroll
      for (int m = 0; m < 4; ++m)
#pragma unroll
        for (int n = 0; n < 4; ++n)
          acc[m][n] = __builtin_amdgcn_mfma_f32_16x16x32_bf16(afh[m], bfh[n], acc[m][n], 0, 0, 0);
      __builtin_amdgcn_s_setprio(0);
      __syncthreads();
      buf ^= 1;
    }
  }

  int orow0 = bm * 128 + wr * 64 + (lane >> 4) * 4;
  if (bn < 20) {
    // RoPE + split epilogue. d = wc*64 + n*16 + ln15; partner d+-32 is acc[m][n+-2].
    int nh = (bn < 16) ? Hdim : HKVdim;
    int h  = (bn < 16) ? bn : bn - 16;
    unsigned short* oph = (bn < 16) ? qhi : khi;
    unsigned short* opl = (bn < 16) ? qlo : klo;
#pragma unroll
    for (int m = 0; m < 4; ++m)
#pragma unroll
      for (int r = 0; r < 4; ++r) {
        int row = orow0 + m * 16 + r;
        int t = row & (Tdim - 1), b = row >> 11;
        size_t obase = (((size_t)(b * nh + h)) * Tdim + t) * 128;
#pragma unroll
        for (int n = 0; n < 4; ++n) {
          int d = wc * 64 + n * 16 + ln15;
          float o;
          if (wc == 0) {
            float c = cs[t * 64 + d], s = sn[t * 64 + d];
            o = (n < 2) ? (acc[m][n][r] * c - acc[m][n + 2][r] * s)
                        : (acc[m][n][r] * c + acc[m][n - 2][r] * s);
          } else o = acc[m][n][r];
          unsigned short hb = f2bf(o);
          oph[obase + d] = hb;
          opl[obase + d] = f2bf(o - bf2f(hb));
        }
      }
  } else {
    // v epilogue: write TRANSPOSED (b,g,d,t) directly; acc[m][n][0..3] = 4
    // consecutive t for one d -> ushort4 store.
    int g = bn - 20;
#pragma unroll
    for (int m = 0; m < 4; ++m) {
      int row0 = orow0 + m * 16;               // multiple of 4
      int t0 = row0 & (Tdim - 1), b = row0 >> 11;
#pragma unroll
      for (int n = 0; n < 4; ++n) {
        int d = wc * 64 + n * 16 + ln15;
        ushort4 v4;
        v4.x = f2bf(acc[m][n][0]);
        v4.y = f2bf(acc[m][n][1]);
        v4.z = f2bf(acc[m][n][2]);
        v4.w = f2bf(acc[m][n][3]);
        *(ushort4*)&vt[(((size_t)(b * HKVdim + g)) * 128 + d) * Tdim + t0] = v4;
      }
    }
  }
}

// ---------------- Wo GEMM: out(M,2048) = yb(M,2048) @ WoT^T, fp32 out, dbuf ----------
__global__ __launch_bounds__(256) void gemm_wo_kernel(
    const unsigned short* __restrict__ A, const unsigned short* __restrict__ Bt,
    float* __restrict__ C)
{
  __shared__ alignas(16) unsigned short sA[2][128 * 32];
  __shared__ alignas(16) unsigned short sB[2][128 * 32];
  const int K = 2048, ldc = 2048;
  int tid = threadIdx.x;
  int wid = tid >> 6, lane = tid & 63;
  int bm = blockIdx.x, bn = blockIdx.y;
  int wr = wid >> 1, wc = wid & 1;
  int ln15 = lane & 15;
  int jsw = (((lane >> 4) ^ ((ln15 >> 1) & 3)) * 8);
  int srow = lane >> 2;
  int scol = (((lane & 3) ^ ((lane >> 3) & 3)) * 8);

  f32x4 acc[4][4];
#pragma unroll
  for (int m = 0; m < 4; ++m)
#pragma unroll
    for (int n = 0; n < 4; ++n)
      acc[m][n] = f32x4{0.f, 0.f, 0.f, 0.f};

  const unsigned short* a0 = A + (size_t)(bm * 128 + wid * 32 + srow) * K + scol;
  const unsigned short* b0 = Bt + (size_t)(bn * 128 + wid * 32 + srow) * K + scol;
  int wlds = wid * 32 * 32;

  auto stage = [&](int buf, int kt) {
    const unsigned short* ak = a0 + kt * 32;
    const unsigned short* bk = b0 + kt * 32;
    GLOAD16(ak,          &sA[buf][wlds]);
    GLOAD16(ak + 16 * K, &sA[buf][wlds + 16 * 32]);
    GLOAD16(bk,          &sB[buf][wlds]);
    GLOAD16(bk + 16 * K, &sB[buf][wlds + 16 * 32]);
  };
  int nk = K >> 5;
  stage(0, 0);
  __syncthreads();
  int buf = 0;
  for (int kt = 0; kt < nk; ++kt) {
    bf16x8 af[4], bfv[4];
#pragma unroll
    for (int m = 0; m < 4; ++m)
      af[m] = *(const bf16x8*)&sA[buf][(wr * 64 + m * 16 + ln15) * 32 + jsw];
#pragma unroll
    for (int n = 0; n < 4; ++n)
      bfv[n] = *(const bf16x8*)&sB[buf][(wc * 64 + n * 16 + ln15) * 32 + jsw];
    if (kt + 1 < nk) stage(buf ^ 1, kt + 1);
    __builtin_amdgcn_s_setprio(1);
#pragma unroll
    for (int m = 0; m < 4; ++m)
#pragma unroll
      for (int n = 0; n < 4; ++n)
        acc[m][n] = __builtin_amdgcn_mfma_f32_16x16x32_bf16(af[m], bfv[n], acc[m][n], 0, 0, 0);
    __builtin_amdgcn_s_setprio(0);
    __syncthreads();
    buf ^= 1;
  }

  int orow0 = bm * 128 + wr * 64 + (lane >> 4) * 4;
  int ocol0 = bn * 128 + wc * 64 + ln15;
#pragma unroll
  for (int m = 0; m < 4; ++m)
#pragma unroll
    for (int n = 0; n < 4; ++n)
#pragma unroll
      for (int r = 0; r < 4; ++r)
        C[(size_t)(orow0 + m * 16 + r) * ldc + ocol0 + n * 16] = acc[m][n][r];
}

// ---------------- fused causal GQA attention with post-softmax gate ----------------
// QBLK=256, 16 waves (1024 thr), each wave owns 16 q-rows. Fixed-M softmax (M=8).
// Two-pass. Pass B iterates a COMPACTED list of live k-blocks (union over waves of
// the per-wave gate test) -- dead blocks cost zero staging/barriers. Bit-identical:
// waves still apply their own per-block test; processing order unchanged (ascending).
// launch_bounds(1024,4): r11 showed tighter bounds force VGPR spills (VGPR=40, 2x slow).
__global__ __launch_bounds__(1024, 4) void attn_kernel(
    const unsigned short* __restrict__ qhi, const unsigned short* __restrict__ qlo,
    const unsigned short* __restrict__ khi, const unsigned short* __restrict__ klo,
    const unsigned short* __restrict__ vt, const float* __restrict__ gate,
    unsigned short* __restrict__ y)
{
  __shared__ alignas(16) unsigned short sKh[2][KT * 128];
  __shared__ alignas(16) unsigned short sKl[2][KT * 128];
  __shared__ alignas(16) unsigned short sV[2][128 * KT];
  __shared__ alignas(16) unsigned short sP[16][16 * 40];
  __shared__ float sBM[16][64];
  __shared__ int liveFlag[64];
  __shared__ int sList[64];
  __shared__ int sCount;

  int qb = (gridDim.x - 1) - blockIdx.x;     // heavy blocks first
  int bh = blockIdx.y;
  int b = bh >> 4, h = bh & 15;
  int g = h >> 2;
  int t0 = qb * 256;
  int tid = threadIdx.x, wid = tid >> 6, lane = tid & 63;
  int ln15 = lane & 15, j16 = (lane >> 4) * 16, ro4 = (lane >> 4) * 4;
  const float cs2 = 0.08838834764831845f * 1.4426950408889634f;  // scale*log2(e)
  const float M2  = 8.0f * 1.4426950408889634f;

  const unsigned short* kh_base = khi + (((size_t)b * HKVdim + g) * Tdim) * 128;
  const unsigned short* kl_base = klo + (((size_t)b * HKVdim + g) * Tdim) * 128;
  const unsigned short* v_base  = vt  + (((size_t)b * HKVdim + g) * 128) * (size_t)Tdim;

  if (tid < 64) liveFlag[tid] = 0;

  bf16x8 aqh[4], aql[4];
  {
    size_t qoff = ((((size_t)b * Hdim + h) * Tdim) + t0 + wid * 16 + ln15) * 128 + (lane >> 4) * 8;
#pragma unroll
    for (int kf = 0; kf < 4; ++kf) {
      aqh[kf] = *(const bf16x8*)(qhi + qoff + kf * 32);
      aql[kf] = *(const bf16x8*)(qlo + qoff + kf * 32);
    }
  }
  float thr = 1.f / (1.f + expf(-gate[h]));

  int nkb = (qb + 1) * 8;
  int tq_lo = t0 + wid * 16;

  auto stageK = [&](int buf, int kb) {
    if (wid < 8) {
      int o = wid * 1024 + lane * 16;
      int row = o >> 8;
      int col = (o & 255) ^ ((row & 7) << 4);
      size_t goff = ((size_t)(kb * KT + row)) * 256 + col;
      GLOAD16((const char*)kh_base + goff, (char*)sKh[buf] + wid * 1024);
      GLOAD16((const char*)kl_base + goff, (char*)sKl[buf] + wid * 1024);
    }
  };
  auto stageV = [&](int buf, int kb) {
    if (wid >= 8) {
      int o = (wid - 8) * 1024 + lane * 16;
      int row = o >> 6;
      int col = (o & 63) ^ (((row ^ (row >> 2)) & 3) << 4);
      size_t goff = (size_t)row * (Tdim * 2) + (size_t)kb * 64 + col;
      GLOAD16((const char*)v_base + goff, (char*)sV[buf] + (wid - 8) * 1024);
    }
  };
  auto qk = [&](int buf, f32x4* s) {
    __builtin_amdgcn_s_setprio(1);
#pragma unroll
    for (int nf = 0; nf < 2; ++nf) {
      f32x4 a = {0.f, 0.f, 0.f, 0.f};
      int krow = nf * 16 + ln15;
      int sw = (krow & 7) << 4;
#pragma unroll
      for (int kf = 0; kf < 4; ++kf) {
        int boff = (kf * 64 + j16) ^ sw;
        bf16x8 bh_ = *(const bf16x8*)((const char*)sKh[buf] + krow * 256 + boff);
        bf16x8 bl_ = *(const bf16x8*)((const char*)sKl[buf] + krow * 256 + boff);
        a = __builtin_amdgcn_mfma_f32_16x16x32_bf16(aqh[kf], bh_, a, 0, 0, 0);
        a = __builtin_amdgcn_mfma_f32_16x16x32_bf16(aql[kf], bh_, a, 0, 0, 0);
        a = __builtin_amdgcn_mfma_f32_16x16x32_bf16(aqh[kf], bl_, a, 0, 0, 0);
      }
      s[nf] = a;
    }
    __builtin_amdgcn_s_setprio(0);
  };

  float lloc[4];
#pragma unroll
  for (int r = 0; r < 4; ++r) lloc[r] = 0.f;

  // ---- PASS A: l = sum 2^(s2-M2); per-block wave max for pass-B skip ----
  stageK(0, 0);
  __syncthreads();
  for (int kb = 0; kb < nkb; ++kb) {
    int buf = kb & 1;
    if (kb + 1 < nkb) stageK(buf ^ 1, kb + 1);
    if (kb * KT <= tq_lo + 15) {
      f32x4 s[2];
      qk(buf, s);
      float wmax = -1e30f;
      bool full = (kb * KT + KT - 1) <= tq_lo;   // wave-uniform: no masked entries
      if (full) {
#pragma unroll
        for (int nf = 0; nf < 2; ++nf)
#pragma unroll
          for (int r = 0; r < 4; ++r) {
            float v = s[nf][r] * cs2;
            wmax = fmaxf(wmax, v);
            lloc[r] += __builtin_exp2f(v - M2);
          }
      } else {
#pragma unroll
        for (int nf = 0; nf < 2; ++nf) {
          int tk = kb * KT + nf * 16 + ln15;
#pragma unroll
          for (int r = 0; r < 4; ++r) {
            int tq = tq_lo + ro4 + r;
            float v = (tk <= tq) ? s[nf][r] * cs2 : -1e30f;
            wmax = fmaxf(wmax, v);
            lloc[r] += __builtin_exp2f(v - M2);   // exp2(-1e30) == 0
          }
        }
      }
#pragma unroll
      for (int off = 1; off < 64; off <<= 1)
        wmax = fmaxf(wmax, __shfl_xor(wmax, off));
      if (lane == 0) sBM[wid][kb] = wmax;
    }
    __syncthreads();
  }

  // merge l across the 16 k-residue lanes (bits 0-3); build log2-space gate
  float lrow[4], lgate2[4];
#pragma unroll
  for (int r = 0; r < 4; ++r) {
    float l = lloc[r];
#pragma unroll
    for (int off = 1; off < 16; off <<= 1) l += __shfl_xor(l, off);
    lrow[r] = l;
    lgate2[r] = __log2f(thr * l) + M2;           // keep iff s2 >= lgate2
  }
  float lgmin = fminf(fminf(lgate2[0], lgate2[1]), fminf(lgate2[2], lgate2[3]));
  lgmin = fminf(lgmin, __shfl_xor(lgmin, 16));
  lgmin = fminf(lgmin, __shfl_xor(lgmin, 32));

  // ---- build compacted live-block list (union over waves) ----
  if (lane == 0) {
    for (int kb = 0; kb < nkb; ++kb)
      if (kb * KT <= tq_lo + 15 && sBM[wid][kb] >= lgmin) liveFlag[kb] = 1;
  }
  __syncthreads();
  if (tid == 0) {
    int c = 0;
    for (int kb = 0; kb < nkb; ++kb)
      if (liveFlag[kb]) sList[c++] = kb;
    sCount = c;
  }
  __syncthreads();
  int cnt = sCount;

  // ---- PASS B: iterate live blocks only; per-wave gate test unchanged ----
  f32x4 yacc[8];
#pragma unroll
  for (int n = 0; n < 8; ++n) yacc[n] = f32x4{0.f, 0.f, 0.f, 0.f};

  if (cnt > 0) { stageK(0, sList[0]); stageV(0, sList[0]); }
  __syncthreads();
  for (int i = 0; i < cnt; ++i) {
    int kb = sList[i];
    int buf = i & 1;
    if (i + 1 < cnt) { stageK(buf ^ 1, sList[i + 1]); stageV(buf ^ 1, sList[i + 1]); }
    if (kb * KT <= tq_lo + 15 && sBM[wid][kb] >= lgmin) {
      f32x4 s[2];
      qk(buf, s);
      bool anyk = false;
      float pv[2][4];
      bool full = (kb * KT + KT - 1) <= tq_lo;
#pragma unroll
      for (int nf = 0; nf < 2; ++nf) {
        int tk = kb * KT + nf * 16 + ln15;
#pragma unroll
        for (int r = 0; r < 4; ++r) {
          int tq = tq_lo + ro4 + r;
          float v = s[nf][r] * cs2;
          bool keep = (full || tk <= tq) && (v >= lgate2[r]);
          float p = 0.f;
          if (keep) { p = __builtin_exp2f(v - M2); anyk = true; }
          pv[nf][r] = p;
        }
      }
      if (__any(anyk)) {
#pragma unroll
        for (int nf = 0; nf < 2; ++nf)
#pragma unroll
          for (int r = 0; r < 4; ++r)
            sP[wid][(ro4 + r) * 40 + nf * 16 + ln15] = f2bf(pv[nf][r]);
        __builtin_amdgcn_s_setprio(1);
        bf16x8 pa = *(const bf16x8*)&sP[wid][ln15 * 40 + (lane >> 4) * 8];
#pragma unroll
        for (int nf2 = 0; nf2 < 8; ++nf2) {
          int vrow = nf2 * 16 + ln15;
          int vboff = j16 ^ (((vrow ^ (vrow >> 2)) & 3) << 4);
          bf16x8 vb = *(const bf16x8*)((const char*)sV[buf] + vrow * 64 + vboff);
          yacc[nf2] = __builtin_amdgcn_mfma_f32_16x16x32_bf16(pa, vb, yacc[nf2], 0, 0, 0);
        }
        __builtin_amdgcn_s_setprio(0);
      }
    }
    __syncthreads();
  }

  // epilogue: y (b,t,h,d) bf16
#pragma unroll
  for (int r = 0; r < 4; ++r) {
    int tq = t0 + wid * 16 + ro4 + r;
    float invl = 1.f / lrow[r];
    size_t base = ((size_t)(b * Tdim + tq)) * Cdim + h * 128;
#pragma unroll
    for (int nf2 = 0; nf2 < 8; ++nf2)
      y[base + nf2 * 16 + ln15] = f2bf(yacc[nf2][r] * invl);
  }
}

extern "C" void kernel_launch(void* const* d_in, const int* in_sizes, int n_in,
                              void* d_out, int out_size, void* d_ws, size_t ws_size,
                              hipStream_t stream)
{
  (void)in_sizes; (void)n_in; (void)out_size; (void)ws_size;
  const float* x    = (const float*)d_in[0];
  const float* cosT = (const float*)d_in[1];
  const float* sinT = (const float*)d_in[2];
  const float* Wq   = (const float*)d_in[3];
  const float* Wk   = (const float*)d_in[4];
  const float* Wv   = (const float*)d_in[5];
  const float* Wo   = (const float*)d_in[6];
  const float* gate = (const float*)d_in[7];
  float* out = (float*)d_out;

  char* ws = (char*)d_ws;
  size_t off = 0;
  auto alloc = [&](size_t bytes) -> char* {
    char* p = ws + off; off += (bytes + 255) & ~(size_t)255; return p;
  };
  const size_t NX = (size_t)Bdim * Tdim * Cdim;    // 8388608
  const size_t NK = (size_t)Bdim * Tdim * KVdim;   // 2097152

  unsigned short* xhi   = (unsigned short*)alloc(NX * 2);
  unsigned short* xlo   = (unsigned short*)alloc(NX * 2);
  unsigned short* WqThi = (unsigned short*)alloc((size_t)Cdim * Cdim * 2);
  unsigned short* WqTlo = (unsigned short*)alloc((size_t)Cdim * Cdim * 2);
  unsigned short* WkThi = (unsigned short*)alloc((size_t)Cdim * KVdim * 2);
  unsigned short* WkTlo = (unsigned short*)alloc((size_t)Cdim * KVdim * 2);
  unsigned short* WvThi = (unsigned short*)alloc((size_t)Cdim * KVdim * 2);
  unsigned short* WoThi = (unsigned short*)alloc((size_t)Cdim * Cdim * 2);
  unsigned short* qhi   = (unsigned short*)alloc(NX * 2);
  unsigned short* qlo   = (unsigned short*)alloc(NX * 2);
  unsigned short* khi   = (unsigned short*)alloc(NK * 2);
  unsigned short* klo   = (unsigned short*)alloc(NK * 2);
  unsigned short* vtr   = (unsigned short*)alloc(NK * 2);
  unsigned short* yb    = (unsigned short*)alloc(NX * 2);

  dim3 tb(32, 8);
  split_x_kernel<<<2048, 256, 0, stream>>>(x, xhi, xlo, (int)(NX >> 2));
  transpose_split2_kernel<<<dim3(64, 64, 2), tb, 0, stream>>>(
      Wq, WqThi, WqTlo, Wo, WoThi, nullptr, Cdim, Cdim);
  transpose_split2_kernel<<<dim3(64, 16, 2), tb, 0, stream>>>(
      Wk, WkThi, WkTlo, Wv, WvThi, nullptr, Cdim, KVdim);

  // q, k (split-3, rope+split fused) and v (1-term, transposed write) in one dispatch
  qkv_gemm_kernel<<<dim3(32, 24), 256, 0, stream>>>(
      xhi, xlo, WqThi, WqTlo, WkThi, WkTlo, WvThi,
      cosT, sinT, qhi, qlo, khi, klo, vtr);

  attn_kernel<<<dim3(8, 32), 1024, 0, stream>>>(qhi, qlo, khi, klo, vtr, gate, yb);

  gemm_wo_kernel<<<dim3(32, 16), 256, 0, stream>>>(yb, WoThi, out);
}